// Round 1
// baseline (417.179 us; speedup 1.0000x reference)
//
#include <hip/hip_runtime.h>

#define N_NODES  100000
#define N_EDGES  1600000
#define N_AGENTS 50000
#define D_EDGE   48
#define D_IN     208
#define D_HID    256
#define D_OUT    64

// ---------------------------------------------------------------------------
// Kernel 1: scatter-sum edge_attr into agg[row] (one thread per edge-feature
// element; edge_attr reads fully coalesced, atomics scattered by row).
// ---------------------------------------------------------------------------
__global__ __launch_bounds__(256)
void scatter_kernel(const float* __restrict__ edge_attr,
                    const int* __restrict__ row,
                    float* __restrict__ agg) {
    int i = blockIdx.x * 256 + threadIdx.x;            // < 76.8M, fits int32
    int total = N_EDGES * D_EDGE;
    if (i >= total) return;
    int e = i / D_EDGE;
    int c = i - e * D_EDGE;
    int r = row[e];
    atomicAdd(&agg[(long long)r * D_EDGE + c], edge_attr[i]);
}

// ---------------------------------------------------------------------------
// Kernel 2: fused gather + concat + MLP.
// 16 agents per 256-thread workgroup.
//  Phase 1: gather [16][208] features into LDS.
//  Phase 2: thread j computes hidden unit j for all 16 agents
//           (W1 column loads coalesced across threads; feature reads are
//            wave-uniform LDS broadcasts, float4-vectorized).
//  Phase 3: 4 groups of 64 threads; group g computes outputs for agents
//           4g..4g+3 (W2 loads coalesced within each 64-lane group).
// ---------------------------------------------------------------------------
__global__ __launch_bounds__(256)
void mlp_kernel(const float* __restrict__ x,
                const float* __restrict__ x_lstm,
                const float* __restrict__ z,
                const float* __restrict__ agg,
                const int* __restrict__ node_idx,
                const float* __restrict__ W1,
                const float* __restrict__ b1,
                const float* __restrict__ W2,
                const float* __restrict__ b2,
                float* __restrict__ out) {
    __shared__ float feat[16][D_IN];    // 13,312 B (rows 832 B, 16B-aligned)
    __shared__ float hbuf[16][D_HID];   // 16,384 B
    __shared__ int   nidx[16];

    const int tid = threadIdx.x;
    const int ag0 = blockIdx.x * 16;

    if (tid < 16) nidx[tid] = node_idx[ag0 + tid];
    __syncthreads();

    // ---- Phase 1: gather features into LDS ----
    for (int i = tid; i < 16 * D_IN; i += 256) {
        int a = i / D_IN;
        int k = i - a * D_IN;
        int ag = ag0 + a;
        float v;
        if (k < 64)       v = x[(long long)nidx[a] * 64 + k];
        else if (k < 128) v = x_lstm[(long long)ag * 64 + (k - 64)];
        else if (k < 160) v = z[(long long)ag * 32 + (k - 128)];
        else              v = agg[(long long)nidx[a] * D_EDGE + (k - 160)];
        feat[a][k] = v;
    }
    __syncthreads();

    // ---- Phase 2: layer 1 (208 -> 256) + ReLU ----
    {
        const int j = tid;                 // hidden unit
        float acc[16];
        #pragma unroll
        for (int a = 0; a < 16; ++a) acc[a] = 0.f;

        for (int k4 = 0; k4 < D_IN / 4; ++k4) {   // 52 iterations
            const int k = k4 * 4;
            float w0 = W1[(k + 0) * D_HID + j];
            float w1 = W1[(k + 1) * D_HID + j];
            float w2 = W1[(k + 2) * D_HID + j];
            float w3 = W1[(k + 3) * D_HID + j];
            #pragma unroll
            for (int a = 0; a < 16; ++a) {
                float4 f = *reinterpret_cast<const float4*>(&feat[a][k]);
                acc[a] = fmaf(f.x, w0, acc[a]);
                acc[a] = fmaf(f.y, w1, acc[a]);
                acc[a] = fmaf(f.z, w2, acc[a]);
                acc[a] = fmaf(f.w, w3, acc[a]);
            }
        }
        float bb = b1[j];
        #pragma unroll
        for (int a = 0; a < 16; ++a) {
            hbuf[a][j] = fmaxf(acc[a] + bb, 0.f);
        }
    }
    __syncthreads();

    // ---- Phase 3: layer 2 (256 -> 64) ----
    {
        const int o = tid & 63;
        const int g = tid >> 6;            // wave-uniform: agents 4g..4g+3
        float acc2[4] = {0.f, 0.f, 0.f, 0.f};

        for (int j4 = 0; j4 < D_HID / 4; ++j4) {  // 64 iterations
            const int jj = j4 * 4;
            float w0 = W2[(jj + 0) * D_OUT + o];
            float w1 = W2[(jj + 1) * D_OUT + o];
            float w2v = W2[(jj + 2) * D_OUT + o];
            float w3 = W2[(jj + 3) * D_OUT + o];
            #pragma unroll
            for (int aa = 0; aa < 4; ++aa) {
                float4 h = *reinterpret_cast<const float4*>(&hbuf[g * 4 + aa][jj]);
                acc2[aa] = fmaf(h.x, w0, acc2[aa]);
                acc2[aa] = fmaf(h.y, w1, acc2[aa]);
                acc2[aa] = fmaf(h.z, w2v, acc2[aa]);
                acc2[aa] = fmaf(h.w, w3, acc2[aa]);
            }
        }
        float bo = b2[o];
        #pragma unroll
        for (int aa = 0; aa < 4; ++aa) {
            out[(long long)(ag0 + g * 4 + aa) * D_OUT + o] = acc2[aa] + bo;
        }
    }
}

extern "C" void kernel_launch(void* const* d_in, const int* in_sizes, int n_in,
                              void* d_out, int out_size, void* d_ws, size_t ws_size,
                              hipStream_t stream) {
    const float* x        = (const float*)d_in[0];
    const float* x_lstm   = (const float*)d_in[1];
    const float* z        = (const float*)d_in[2];
    const int*   edge_idx = (const int*)d_in[3];   // [2][N_EDGES]; row = first half
    const float* edge_attr= (const float*)d_in[4];
    const int*   node_idx = (const int*)d_in[5];
    const float* W1       = (const float*)d_in[6];
    const float* b1       = (const float*)d_in[7];
    const float* W2       = (const float*)d_in[8];
    const float* b2       = (const float*)d_in[9];
    float* out = (float*)d_out;

    float* agg = (float*)d_ws;                     // N_NODES * 48 f32 = 19.2 MB

    hipMemsetAsync(agg, 0, (size_t)N_NODES * D_EDGE * sizeof(float), stream);

    const int total = N_EDGES * D_EDGE;            // 76,800,000
    const int nblk = (total + 255) / 256;          // 300,000
    scatter_kernel<<<nblk, 256, 0, stream>>>(edge_attr, edge_idx, agg);

    mlp_kernel<<<N_AGENTS / 16, 256, 0, stream>>>(x, x_lstm, z, agg, node_idx,
                                                  W1, b1, W2, b2, out);
}

// Round 2
// 360.733 us; speedup vs baseline: 1.1565x; 1.1565x over previous
//
#include <hip/hip_runtime.h>

#define N_NODES  100000
#define N_EDGES  1600000
#define N_AGENTS 50000
#define D_EDGE   48
#define D_IN     208
#define D_HID    256
#define D_OUT    64

typedef float v2f __attribute__((ext_vector_type(2)));

// ---------------------------------------------------------------------------
// Kernel 0: mark nodes that any agent references (races benign: all write 1).
// ---------------------------------------------------------------------------
__global__ __launch_bounds__(256)
void mask_kernel(const int* __restrict__ node_idx,
                 unsigned char* __restrict__ mask) {
    int i = blockIdx.x * 256 + threadIdx.x;
    if (i < N_AGENTS) mask[node_idx[i]] = 1;
}

// ---------------------------------------------------------------------------
// Kernel 1: scatter-sum edge_attr into agg[row], skipping edges whose target
// node no agent reads (~61%). One thread per (edge, channel-pair); packed
// v2f32 atomics when available (one L2 atomic op per 8B instead of per 4B).
// ---------------------------------------------------------------------------
__global__ __launch_bounds__(256)
void scatter_kernel(const float* __restrict__ edge_attr,
                    const int* __restrict__ row,
                    const unsigned char* __restrict__ mask,
                    float* __restrict__ agg) {
    int i = blockIdx.x * 256 + threadIdx.x;        // < 38.4M
    const int total = N_EDGES * (D_EDGE / 2);
    if (i >= total) return;
    int e = i / (D_EDGE / 2);                      // edge
    int p = i - e * (D_EDGE / 2);                  // pair index 0..23
    int r = row[e];
    if (!mask[r]) return;
    v2f v = *reinterpret_cast<const v2f*>(&edge_attr[(long long)e * D_EDGE + p * 2]);
    float* dst = &agg[(long long)r * D_EDGE + p * 2];
#if __has_builtin(__builtin_amdgcn_global_atomic_fadd_v2f32)
    __builtin_amdgcn_global_atomic_fadd_v2f32((v2f*)dst, v);
#else
    atomicAdd(dst + 0, v.x);
    atomicAdd(dst + 1, v.y);
#endif
}

// ---------------------------------------------------------------------------
// Kernel 2: fused gather + concat + MLP. 16 agents per 256-thread block.
//  Phase 2 blocking: each thread computes 4 hidden units x 4 agents
//  (16 FMA per ds_read_b128 -> FMA-bound, not LDS-issue-bound).
// ---------------------------------------------------------------------------
__global__ __launch_bounds__(256)
void mlp_kernel(const float* __restrict__ x,
                const float* __restrict__ x_lstm,
                const float* __restrict__ z,
                const float* __restrict__ agg,
                const int* __restrict__ node_idx,
                const float* __restrict__ W1,
                const float* __restrict__ b1,
                const float* __restrict__ W2,
                const float* __restrict__ b2,
                float* __restrict__ out) {
    __shared__ float feat[16][D_IN];    // 13,312 B
    __shared__ float hbuf[16][D_HID];   // 16,384 B
    __shared__ int   nidx[16];

    const int tid = threadIdx.x;
    const int ag0 = blockIdx.x * 16;

    if (tid < 16) nidx[tid] = node_idx[ag0 + tid];
    __syncthreads();

    // ---- Phase 1: gather features into LDS ----
    for (int i = tid; i < 16 * D_IN; i += 256) {
        int a = i / D_IN;
        int k = i - a * D_IN;
        int ag = ag0 + a;
        float v;
        if (k < 64)       v = x[(long long)nidx[a] * 64 + k];
        else if (k < 128) v = x_lstm[(long long)ag * 64 + (k - 64)];
        else if (k < 160) v = z[(long long)ag * 32 + (k - 128)];
        else              v = agg[(long long)nidx[a] * D_EDGE + (k - 160)];
        feat[a][k] = v;
    }
    __syncthreads();

    // ---- Phase 2: layer 1 (208 -> 256) + ReLU; 4 units x 4 agents/thread ----
    {
        const int u  = (tid & 63) * 4;   // unit quad (64 lanes cover 256 units)
        const int ga = (tid >> 6) * 4;   // agent quad (4 waves cover 16 agents)

        float acc[4][4];
        #pragma unroll
        for (int a = 0; a < 4; ++a)
            #pragma unroll
            for (int q = 0; q < 4; ++q) acc[a][q] = 0.f;

        for (int k4 = 0; k4 < D_IN / 4; ++k4) {   // 52 iterations
            const int k = k4 * 4;
            float4 w0 = *reinterpret_cast<const float4*>(&W1[(k + 0) * D_HID + u]);
            float4 w1 = *reinterpret_cast<const float4*>(&W1[(k + 1) * D_HID + u]);
            float4 w2 = *reinterpret_cast<const float4*>(&W1[(k + 2) * D_HID + u]);
            float4 w3 = *reinterpret_cast<const float4*>(&W1[(k + 3) * D_HID + u]);
            #pragma unroll
            for (int a = 0; a < 4; ++a) {
                float4 f = *reinterpret_cast<const float4*>(&feat[ga + a][k]);
                #pragma unroll
                for (int q = 0; q < 4; ++q) {
                    float wq0 = (&w0.x)[q], wq1 = (&w1.x)[q],
                          wq2 = (&w2.x)[q], wq3 = (&w3.x)[q];
                    acc[a][q] = fmaf(f.x, wq0, acc[a][q]);
                    acc[a][q] = fmaf(f.y, wq1, acc[a][q]);
                    acc[a][q] = fmaf(f.z, wq2, acc[a][q]);
                    acc[a][q] = fmaf(f.w, wq3, acc[a][q]);
                }
            }
        }
        float4 bb = *reinterpret_cast<const float4*>(&b1[u]);
        #pragma unroll
        for (int a = 0; a < 4; ++a) {
            float4 h;
            h.x = fmaxf(acc[a][0] + bb.x, 0.f);
            h.y = fmaxf(acc[a][1] + bb.y, 0.f);
            h.z = fmaxf(acc[a][2] + bb.z, 0.f);
            h.w = fmaxf(acc[a][3] + bb.w, 0.f);
            *reinterpret_cast<float4*>(&hbuf[ga + a][u]) = h;
        }
    }
    __syncthreads();

    // ---- Phase 3: layer 2 (256 -> 64); 4 agents/thread ----
    {
        const int o = tid & 63;
        const int g = tid >> 6;
        float acc2[4] = {0.f, 0.f, 0.f, 0.f};

        for (int j4 = 0; j4 < D_HID / 4; ++j4) {  // 64 iterations
            const int jj = j4 * 4;
            float w0 = W2[(jj + 0) * D_OUT + o];
            float w1 = W2[(jj + 1) * D_OUT + o];
            float w2v = W2[(jj + 2) * D_OUT + o];
            float w3 = W2[(jj + 3) * D_OUT + o];
            #pragma unroll
            for (int aa = 0; aa < 4; ++aa) {
                float4 h = *reinterpret_cast<const float4*>(&hbuf[g * 4 + aa][jj]);
                acc2[aa] = fmaf(h.x, w0, acc2[aa]);
                acc2[aa] = fmaf(h.y, w1, acc2[aa]);
                acc2[aa] = fmaf(h.z, w2v, acc2[aa]);
                acc2[aa] = fmaf(h.w, w3, acc2[aa]);
            }
        }
        float bo = b2[o];
        #pragma unroll
        for (int aa = 0; aa < 4; ++aa) {
            out[(long long)(ag0 + g * 4 + aa) * D_OUT + o] = acc2[aa] + bo;
        }
    }
}

extern "C" void kernel_launch(void* const* d_in, const int* in_sizes, int n_in,
                              void* d_out, int out_size, void* d_ws, size_t ws_size,
                              hipStream_t stream) {
    const float* x        = (const float*)d_in[0];
    const float* x_lstm   = (const float*)d_in[1];
    const float* z        = (const float*)d_in[2];
    const int*   edge_idx = (const int*)d_in[3];   // [2][N_EDGES]; row = first half
    const float* edge_attr= (const float*)d_in[4];
    const int*   node_idx = (const int*)d_in[5];
    const float* W1       = (const float*)d_in[6];
    const float* b1       = (const float*)d_in[7];
    const float* W2       = (const float*)d_in[8];
    const float* b2       = (const float*)d_in[9];
    float* out = (float*)d_out;

    float* agg = (float*)d_ws;                               // 19.2 MB
    unsigned char* mask = (unsigned char*)d_ws + (size_t)N_NODES * D_EDGE * sizeof(float);

    hipMemsetAsync(agg, 0, (size_t)N_NODES * D_EDGE * sizeof(float), stream);
    hipMemsetAsync(mask, 0, N_NODES, stream);

    mask_kernel<<<(N_AGENTS + 255) / 256, 256, 0, stream>>>(node_idx, mask);

    const int total = N_EDGES * (D_EDGE / 2);                // 38,400,000
    scatter_kernel<<<(total + 255) / 256, 256, 0, stream>>>(edge_attr, edge_idx, mask, agg);

    mlp_kernel<<<N_AGENTS / 16, 256, 0, stream>>>(x, x_lstm, z, agg, node_idx,
                                                  W1, b1, W2, b2, out);
}

// Round 3
// 273.711 us; speedup vs baseline: 1.5242x; 1.3179x over previous
//
#include <hip/hip_runtime.h>

#define N_NODES  100000
#define N_EDGES  1600000
#define N_AGENTS 50000
#define D_EDGE   48
#define D_IN     208
#define D_HID    256
#define D_OUT    64

#define SCAN_ITEMS  1024
#define SCAN_BLOCKS ((N_NODES + SCAN_ITEMS - 1) / SCAN_ITEMS)   // 98
#define BUCKET_CAP  700000   // E[masked edges]=629.6K, sigma~620 -> >100 sigma margin

// ---------------------------------------------------------------------------
// Mark nodes referenced by any agent (races benign: all write 1).
// ---------------------------------------------------------------------------
__global__ __launch_bounds__(256)
void mask_kernel(const int* __restrict__ node_idx, unsigned char* __restrict__ mask) {
    int i = blockIdx.x * 256 + threadIdx.x;
    if (i < N_AGENTS) mask[node_idx[i]] = 1;
}

// ---------------------------------------------------------------------------
// Histogram of masked rows.
// ---------------------------------------------------------------------------
__global__ __launch_bounds__(256)
void hist_kernel(const int* __restrict__ row, const unsigned char* __restrict__ mask,
                 int* __restrict__ cnt) {
    int e = blockIdx.x * 256 + threadIdx.x;
    if (e >= N_EDGES) return;
    int r = row[e];
    if (mask[r]) atomicAdd(&cnt[r], 1);
}

// ---------------------------------------------------------------------------
// Device-wide exclusive scan over cnt[N_NODES] -> off[], 3 launches.
// ---------------------------------------------------------------------------
__global__ __launch_bounds__(256)
void scan_a(const int* __restrict__ cnt, int* __restrict__ off, int* __restrict__ bsum) {
    __shared__ int s[256];
    const int b = blockIdx.x, t = threadIdx.x;
    const int base = b * SCAN_ITEMS + t * 4;
    int v[4];
    #pragma unroll
    for (int k = 0; k < 4; ++k) {
        int idx = base + k;
        v[k] = (idx < N_NODES) ? cnt[idx] : 0;
    }
    int tsum = v[0] + v[1] + v[2] + v[3];
    s[t] = tsum;
    __syncthreads();
    for (int d = 1; d < 256; d <<= 1) {
        int x = (t >= d) ? s[t - d] : 0;
        __syncthreads();
        s[t] += x;
        __syncthreads();
    }
    int run = s[t] - tsum;               // exclusive prefix of this thread
    if (t == 255) bsum[b] = s[255];      // block total
    #pragma unroll
    for (int k = 0; k < 4; ++k) {
        int idx = base + k;
        if (idx < N_NODES) off[idx] = run;
        run += v[k];
    }
}

__global__ __launch_bounds__(128)
void scan_b(int* __restrict__ bsum) {
    __shared__ int s[128];
    const int t = threadIdx.x;
    int v = (t < SCAN_BLOCKS) ? bsum[t] : 0;
    s[t] = v;
    __syncthreads();
    for (int d = 1; d < 128; d <<= 1) {
        int x = (t >= d) ? s[t - d] : 0;
        __syncthreads();
        s[t] += x;
        __syncthreads();
    }
    if (t < SCAN_BLOCKS) bsum[t] = s[t] - v;   // exclusive
}

__global__ __launch_bounds__(256)
void scan_c(int* __restrict__ off, const int* __restrict__ bsum) {
    int i = blockIdx.x * 256 + threadIdx.x;
    if (i < N_NODES) off[i] += bsum[i / SCAN_ITEMS];
}

// ---------------------------------------------------------------------------
// Place masked edge ids into per-node buckets.
// ---------------------------------------------------------------------------
__global__ __launch_bounds__(256)
void place_kernel(const int* __restrict__ row, const unsigned char* __restrict__ mask,
                  const int* __restrict__ off, int* __restrict__ cur,
                  int* __restrict__ bucket) {
    int e = blockIdx.x * 256 + threadIdx.x;
    if (e >= N_EDGES) return;
    int r = row[e];
    if (!mask[r]) return;
    int pos = atomicAdd(&cur[r], 1);
    int idx = off[r] + pos;
    if (idx < BUCKET_CAP) bucket[idx] = e;
}

// ---------------------------------------------------------------------------
// Gather-sum: thread = (node, channel). Reads each kept edge_attr row once
// (coalesced 192B across the 48-thread channel group), writes agg once.
// ---------------------------------------------------------------------------
__global__ __launch_bounds__(256)
void gather_kernel(const float* __restrict__ edge_attr,
                   const unsigned char* __restrict__ mask,
                   const int* __restrict__ off, const int* __restrict__ cnt,
                   const int* __restrict__ bucket,
                   float* __restrict__ agg) {
    int gid = blockIdx.x * 256 + threadIdx.x;
    if (gid >= N_NODES * D_EDGE) return;
    int n = gid / D_EDGE;
    int c = gid - n * D_EDGE;
    if (!mask[n]) return;                 // never read by MLP
    int deg = cnt[n];
    int base = off[n];
    float acc = 0.f;
    int j = 0;
    for (; j + 4 <= deg; j += 4) {
        int e0 = bucket[base + j + 0];
        int e1 = bucket[base + j + 1];
        int e2 = bucket[base + j + 2];
        int e3 = bucket[base + j + 3];
        float a0 = edge_attr[(long long)e0 * D_EDGE + c];
        float a1 = edge_attr[(long long)e1 * D_EDGE + c];
        float a2 = edge_attr[(long long)e2 * D_EDGE + c];
        float a3 = edge_attr[(long long)e3 * D_EDGE + c];
        acc += (a0 + a1) + (a2 + a3);
    }
    for (; j < deg; ++j) {
        int e0 = bucket[base + j];
        acc += edge_attr[(long long)e0 * D_EDGE + c];
    }
    agg[(long long)n * D_EDGE + c] = acc;
}

// ---------------------------------------------------------------------------
// Fused gather + concat + MLP. 16 agents / 256-thread block.
// Phase 2: thread = 2 units x 8 agents; block covers all 256 units so W1 is
// streamed from L2 exactly once per block (212KB); 8 FMA per ds_read_b128.
// ---------------------------------------------------------------------------
__global__ __launch_bounds__(256)
void mlp_kernel(const float* __restrict__ x,
                const float* __restrict__ x_lstm,
                const float* __restrict__ z,
                const float* __restrict__ agg,
                const int* __restrict__ node_idx,
                const float* __restrict__ W1,
                const float* __restrict__ b1,
                const float* __restrict__ W2,
                const float* __restrict__ b2,
                float* __restrict__ out) {
    __shared__ float feat[16][D_IN];    // 13,312 B
    __shared__ float hbuf[16][D_HID];   // 16,384 B
    __shared__ int   nidx[16];

    const int tid = threadIdx.x;
    const int ag0 = blockIdx.x * 16;

    if (tid < 16) nidx[tid] = node_idx[ag0 + tid];
    __syncthreads();

    // ---- Phase 1: gather features into LDS ----
    for (int i = tid; i < 16 * D_IN; i += 256) {
        int a = i / D_IN;
        int k = i - a * D_IN;
        int ag = ag0 + a;
        float v;
        if (k < 64)       v = x[(long long)nidx[a] * 64 + k];
        else if (k < 128) v = x_lstm[(long long)ag * 64 + (k - 64)];
        else if (k < 160) v = z[(long long)ag * 32 + (k - 128)];
        else              v = agg[(long long)nidx[a] * D_EDGE + (k - 160)];
        feat[a][k] = v;
    }
    __syncthreads();

    // ---- Phase 2: layer 1 (208 -> 256) + ReLU ----
    {
        const int p  = (tid & 127) * 2;   // unit pair
        const int ah = (tid >> 7) * 8;    // agent octet

        float acc[8][2];
        #pragma unroll
        for (int a = 0; a < 8; ++a) { acc[a][0] = 0.f; acc[a][1] = 0.f; }

        for (int k4 = 0; k4 < D_IN / 4; ++k4) {   // 52 iterations
            const int k = k4 * 4;
            float2 w0 = *reinterpret_cast<const float2*>(&W1[(k + 0) * D_HID + p]);
            float2 w1 = *reinterpret_cast<const float2*>(&W1[(k + 1) * D_HID + p]);
            float2 w2 = *reinterpret_cast<const float2*>(&W1[(k + 2) * D_HID + p]);
            float2 w3 = *reinterpret_cast<const float2*>(&W1[(k + 3) * D_HID + p]);
            #pragma unroll
            for (int a = 0; a < 8; ++a) {
                float4 f = *reinterpret_cast<const float4*>(&feat[ah + a][k]);
                acc[a][0] = fmaf(f.x, w0.x, acc[a][0]);
                acc[a][0] = fmaf(f.y, w1.x, acc[a][0]);
                acc[a][0] = fmaf(f.z, w2.x, acc[a][0]);
                acc[a][0] = fmaf(f.w, w3.x, acc[a][0]);
                acc[a][1] = fmaf(f.x, w0.y, acc[a][1]);
                acc[a][1] = fmaf(f.y, w1.y, acc[a][1]);
                acc[a][1] = fmaf(f.z, w2.y, acc[a][1]);
                acc[a][1] = fmaf(f.w, w3.y, acc[a][1]);
            }
        }
        float2 bb = *reinterpret_cast<const float2*>(&b1[p]);
        #pragma unroll
        for (int a = 0; a < 8; ++a) {
            float2 h;
            h.x = fmaxf(acc[a][0] + bb.x, 0.f);
            h.y = fmaxf(acc[a][1] + bb.y, 0.f);
            *reinterpret_cast<float2*>(&hbuf[ah + a][p]) = h;
        }
    }
    __syncthreads();

    // ---- Phase 3: layer 2 (256 -> 64); 4 agents/thread ----
    {
        const int o = tid & 63;
        const int g = tid >> 6;
        float acc2[4] = {0.f, 0.f, 0.f, 0.f};

        for (int j4 = 0; j4 < D_HID / 4; ++j4) {  // 64 iterations
            const int jj = j4 * 4;
            float w0 = W2[(jj + 0) * D_OUT + o];
            float w1 = W2[(jj + 1) * D_OUT + o];
            float w2v = W2[(jj + 2) * D_OUT + o];
            float w3 = W2[(jj + 3) * D_OUT + o];
            #pragma unroll
            for (int aa = 0; aa < 4; ++aa) {
                float4 h = *reinterpret_cast<const float4*>(&hbuf[g * 4 + aa][jj]);
                acc2[aa] = fmaf(h.x, w0, acc2[aa]);
                acc2[aa] = fmaf(h.y, w1, acc2[aa]);
                acc2[aa] = fmaf(h.z, w2v, acc2[aa]);
                acc2[aa] = fmaf(h.w, w3, acc2[aa]);
            }
        }
        float bo = b2[o];
        #pragma unroll
        for (int aa = 0; aa < 4; ++aa) {
            out[(long long)(ag0 + g * 4 + aa) * D_OUT + o] = acc2[aa] + bo;
        }
    }
}

extern "C" void kernel_launch(void* const* d_in, const int* in_sizes, int n_in,
                              void* d_out, int out_size, void* d_ws, size_t ws_size,
                              hipStream_t stream) {
    const float* x        = (const float*)d_in[0];
    const float* x_lstm   = (const float*)d_in[1];
    const float* z        = (const float*)d_in[2];
    const int*   edge_idx = (const int*)d_in[3];   // [2][N_EDGES]; row = first half
    const float* edge_attr= (const float*)d_in[4];
    const int*   node_idx = (const int*)d_in[5];
    const float* W1       = (const float*)d_in[6];
    const float* b1       = (const float*)d_in[7];
    const float* W2       = (const float*)d_in[8];
    const float* b2       = (const float*)d_in[9];
    float* out = (float*)d_out;

    // ws layout
    char* w = (char*)d_ws;
    float* agg  = (float*)w;                                   size_t o = (size_t)N_NODES * D_EDGE * 4; // 19.2 MB
    int* cnt    = (int*)(w + o);                               o += (size_t)N_NODES * 4;   // hist
    int* cur    = (int*)(w + o);                               o += (size_t)N_NODES * 4;   // cursor
    int* off    = (int*)(w + o);                               o += (size_t)N_NODES * 4;   // scan
    int* bsum   = (int*)(w + o);                               o += 512;
    int* bucket = (int*)(w + o);                               o += (size_t)BUCKET_CAP * 4;
    unsigned char* mask = (unsigned char*)(w + o);             o += N_NODES;

    hipMemsetAsync(mask, 0, N_NODES, stream);
    hipMemsetAsync(cnt, 0, (size_t)N_NODES * 4, stream);
    hipMemsetAsync(cur, 0, (size_t)N_NODES * 4, stream);

    mask_kernel<<<(N_AGENTS + 255) / 256, 256, 0, stream>>>(node_idx, mask);
    hist_kernel<<<(N_EDGES + 255) / 256, 256, 0, stream>>>(edge_idx, mask, cnt);
    scan_a<<<SCAN_BLOCKS, 256, 0, stream>>>(cnt, off, bsum);
    scan_b<<<1, 128, 0, stream>>>(bsum);
    scan_c<<<(N_NODES + 255) / 256, 256, 0, stream>>>(off, bsum);
    place_kernel<<<(N_EDGES + 255) / 256, 256, 0, stream>>>(edge_idx, mask, off, cur, bucket);
    gather_kernel<<<(N_NODES * D_EDGE + 255) / 256, 256, 0, stream>>>(
        edge_attr, mask, off, cnt, bucket, agg);
    mlp_kernel<<<N_AGENTS / 16, 256, 0, stream>>>(x, x_lstm, z, agg, node_idx,
                                                  W1, b1, W2, b2, out);
}

// Round 4
// 177.663 us; speedup vs baseline: 2.3481x; 1.5406x over previous
//
#include <hip/hip_runtime.h>

#define N_NODES  100000
#define N_EDGES  1600000
#define N_AGENTS 50000
#define D_EDGE   48
#define D_IN     208
#define D_HID    256
#define D_OUT    64

#define K1_PAD   224            // D_IN padded to 7*32 for MFMA K-steps
#define F_STRIDE 248            // feat LDS row stride (bf16) -> 2-way banks max
#define H_STRIDE 280            // hbuf LDS row stride (bf16) -> 2-way banks max
#define W1T_STRIDE 232          // W1t row stride (bf16), 16B-aligned rows

#define SCAN_ITEMS  1024
#define SCAN_BLOCKS ((N_NODES + SCAN_ITEMS - 1) / SCAN_ITEMS)   // 98
#define BUCKET_CAP  700000

typedef __attribute__((ext_vector_type(8))) short short8;   // 8 bf16 = 4 VGPRs
typedef __attribute__((ext_vector_type(4))) float f32x4;

static __device__ __forceinline__ unsigned short f2bf(float f) {
    unsigned u = __float_as_uint(f);
    u += 0x7FFFu + ((u >> 16) & 1u);    // round-to-nearest-even
    return (unsigned short)(u >> 16);
}

// ---------------------------------------------------------------------------
// Weight prep (runs every launch; deterministic). W1t[n][k]=W1[k][n] bf16,
// zero-padded k in [208,232). W2t[o][k]=W2[k][o] bf16.
// ---------------------------------------------------------------------------
__global__ __launch_bounds__(256)
void prep_w1(const float* __restrict__ W1, unsigned short* __restrict__ W1t) {
    int i = blockIdx.x * 256 + threadIdx.x;
    if (i >= D_HID * W1T_STRIDE) return;
    int n = i / W1T_STRIDE;
    int k = i - n * W1T_STRIDE;
    W1t[i] = (k < D_IN) ? f2bf(W1[k * D_HID + n]) : (unsigned short)0;
}

__global__ __launch_bounds__(256)
void prep_w2(const float* __restrict__ W2, unsigned short* __restrict__ W2t) {
    int i = blockIdx.x * 256 + threadIdx.x;
    if (i >= D_OUT * D_HID) return;
    int o = i >> 8;
    int k = i & 255;
    W2t[i] = f2bf(W2[k * D_OUT + o]);
}

// ---------------------------------------------------------------------------
// Edge-aggregation chain (unchanged from round 3).
// ---------------------------------------------------------------------------
__global__ __launch_bounds__(256)
void mask_kernel(const int* __restrict__ node_idx, unsigned char* __restrict__ mask) {
    int i = blockIdx.x * 256 + threadIdx.x;
    if (i < N_AGENTS) mask[node_idx[i]] = 1;
}

__global__ __launch_bounds__(256)
void hist_kernel(const int* __restrict__ row, const unsigned char* __restrict__ mask,
                 int* __restrict__ cnt) {
    int e = blockIdx.x * 256 + threadIdx.x;
    if (e >= N_EDGES) return;
    int r = row[e];
    if (mask[r]) atomicAdd(&cnt[r], 1);
}

__global__ __launch_bounds__(256)
void scan_a(const int* __restrict__ cnt, int* __restrict__ off, int* __restrict__ bsum) {
    __shared__ int s[256];
    const int b = blockIdx.x, t = threadIdx.x;
    const int base = b * SCAN_ITEMS + t * 4;
    int v[4];
    #pragma unroll
    for (int k = 0; k < 4; ++k) {
        int idx = base + k;
        v[k] = (idx < N_NODES) ? cnt[idx] : 0;
    }
    int tsum = v[0] + v[1] + v[2] + v[3];
    s[t] = tsum;
    __syncthreads();
    for (int d = 1; d < 256; d <<= 1) {
        int x = (t >= d) ? s[t - d] : 0;
        __syncthreads();
        s[t] += x;
        __syncthreads();
    }
    int run = s[t] - tsum;
    if (t == 255) bsum[b] = s[255];
    #pragma unroll
    for (int k = 0; k < 4; ++k) {
        int idx = base + k;
        if (idx < N_NODES) off[idx] = run;
        run += v[k];
    }
}

__global__ __launch_bounds__(128)
void scan_b(int* __restrict__ bsum) {
    __shared__ int s[128];
    const int t = threadIdx.x;
    int v = (t < SCAN_BLOCKS) ? bsum[t] : 0;
    s[t] = v;
    __syncthreads();
    for (int d = 1; d < 128; d <<= 1) {
        int x = (t >= d) ? s[t - d] : 0;
        __syncthreads();
        s[t] += x;
        __syncthreads();
    }
    if (t < SCAN_BLOCKS) bsum[t] = s[t] - v;
}

__global__ __launch_bounds__(256)
void scan_c(int* __restrict__ off, const int* __restrict__ bsum) {
    int i = blockIdx.x * 256 + threadIdx.x;
    if (i < N_NODES) off[i] += bsum[i / SCAN_ITEMS];
}

__global__ __launch_bounds__(256)
void place_kernel(const int* __restrict__ row, const unsigned char* __restrict__ mask,
                  const int* __restrict__ off, int* __restrict__ cur,
                  int* __restrict__ bucket) {
    int e = blockIdx.x * 256 + threadIdx.x;
    if (e >= N_EDGES) return;
    int r = row[e];
    if (!mask[r]) return;
    int pos = atomicAdd(&cur[r], 1);
    int idx = off[r] + pos;
    if (idx < BUCKET_CAP) bucket[idx] = e;
}

__global__ __launch_bounds__(256)
void gather_kernel(const float* __restrict__ edge_attr,
                   const unsigned char* __restrict__ mask,
                   const int* __restrict__ off, const int* __restrict__ cnt,
                   const int* __restrict__ bucket,
                   float* __restrict__ agg) {
    int gid = blockIdx.x * 256 + threadIdx.x;
    if (gid >= N_NODES * D_EDGE) return;
    int n = gid / D_EDGE;
    int c = gid - n * D_EDGE;
    if (!mask[n]) return;
    int deg = cnt[n];
    int base = off[n];
    float acc = 0.f;
    int j = 0;
    for (; j + 4 <= deg; j += 4) {
        int e0 = bucket[base + j + 0];
        int e1 = bucket[base + j + 1];
        int e2 = bucket[base + j + 2];
        int e3 = bucket[base + j + 3];
        float a0 = edge_attr[(long long)e0 * D_EDGE + c];
        float a1 = edge_attr[(long long)e1 * D_EDGE + c];
        float a2 = edge_attr[(long long)e2 * D_EDGE + c];
        float a3 = edge_attr[(long long)e3 * D_EDGE + c];
        acc += (a0 + a1) + (a2 + a3);
    }
    for (; j < deg; ++j) {
        int e0 = bucket[base + j];
        acc += edge_attr[(long long)e0 * D_EDGE + c];
    }
    agg[(long long)n * D_EDGE + c] = acc;
}

// ---------------------------------------------------------------------------
// MFMA MLP: 16 agents / 256-thread block (4 waves).
// Layer 1: M=16 agents, N=256 units, K=224 (padded). Wave w owns units
//   [w*64, w*64+64): 4 N-tiles x 7 K-steps of mfma_f32_16x16x32_bf16.
// Layer 2: M=16, N=64, K=256. Wave w owns units [w*16, w*16+16): 8 K-steps.
// Fragment maps (verified per guide): A: row=lane&15, k=(lane>>4)*8+j;
//   B: col=lane&15, same k; C/D: col=lane&15, row=(lane>>4)*4+reg.
// ---------------------------------------------------------------------------
__global__ __launch_bounds__(256)
void mlp_mfma(const float* __restrict__ x,
              const float* __restrict__ x_lstm,
              const float* __restrict__ z,
              const float* __restrict__ agg,
              const int* __restrict__ node_idx,
              const unsigned short* __restrict__ W1t,
              const float* __restrict__ b1,
              const unsigned short* __restrict__ W2t,
              const float* __restrict__ b2,
              float* __restrict__ out) {
    __shared__ unsigned short feat[16][F_STRIDE];   // 7,936 B
    __shared__ unsigned short hbuf[16][H_STRIDE];   // 8,960 B
    __shared__ int nidx[16];

    const int tid = threadIdx.x;
    const int ag0 = blockIdx.x * 16;

    if (tid < 16) nidx[tid] = node_idx[ag0 + tid];
    __syncthreads();

    // ---- gather + bf16-convert features: group of 16 threads per agent ----
    {
        const int a  = tid >> 4;
        const int kt = tid & 15;
        const int nid = nidx[a];
        const int ag  = ag0 + a;
        #pragma unroll
        for (int k = kt; k < K1_PAD; k += 16) {
            float v;
            if (k < 64)       v = x[(long long)nid * 64 + k];
            else if (k < 128) v = x_lstm[(long long)ag * 64 + (k - 64)];
            else if (k < 160) v = z[(long long)ag * 32 + (k - 128)];
            else if (k < 208) v = agg[(long long)nid * D_EDGE + (k - 160)];
            else              v = 0.f;
            feat[a][k] = f2bf(v);
        }
    }
    __syncthreads();

    const int w    = tid >> 6;      // wave 0..3
    const int lane = tid & 63;
    const int m16  = lane & 15;     // tile row (A) / col (B, C/D)
    const int g    = lane >> 4;     // k-group / row-group

    // ---- layer 1 ----
    short8 afrag[7];
    #pragma unroll
    for (int ks = 0; ks < 7; ++ks)
        afrag[ks] = *reinterpret_cast<const short8*>(&feat[m16][ks * 32 + g * 8]);

    #pragma unroll
    for (int nt = 0; nt < 4; ++nt) {
        const int n = w * 64 + nt * 16 + m16;      // unit (B col / D col)
        f32x4 acc = {0.f, 0.f, 0.f, 0.f};
        #pragma unroll
        for (int ks = 0; ks < 7; ++ks) {
            short8 bfrag = *reinterpret_cast<const short8*>(
                &W1t[n * W1T_STRIDE + ks * 32 + g * 8]);
            acc = __builtin_amdgcn_mfma_f32_16x16x32_bf16(afrag[ks], bfrag, acc, 0, 0, 0);
        }
        const float bb = b1[n];
        #pragma unroll
        for (int r = 0; r < 4; ++r) {
            float h = fmaxf(acc[r] + bb, 0.f);
            hbuf[g * 4 + r][n] = f2bf(h);          // row=agent, col=unit
        }
    }
    __syncthreads();

    // ---- layer 2 ----
    {
        const int o = w * 16 + m16;                // output unit
        f32x4 acc = {0.f, 0.f, 0.f, 0.f};
        #pragma unroll
        for (int ks = 0; ks < 8; ++ks) {
            short8 a2 = *reinterpret_cast<const short8*>(&hbuf[m16][ks * 32 + g * 8]);
            short8 b2f = *reinterpret_cast<const short8*>(&W2t[o * D_HID + ks * 32 + g * 8]);
            acc = __builtin_amdgcn_mfma_f32_16x16x32_bf16(a2, b2f, acc, 0, 0, 0);
        }
        const float bo = b2[o];
        #pragma unroll
        for (int r = 0; r < 4; ++r) {
            const int m = g * 4 + r;               // agent row
            out[(long long)(ag0 + m) * D_OUT + o] = acc[r] + bo;
        }
    }
}

extern "C" void kernel_launch(void* const* d_in, const int* in_sizes, int n_in,
                              void* d_out, int out_size, void* d_ws, size_t ws_size,
                              hipStream_t stream) {
    const float* x        = (const float*)d_in[0];
    const float* x_lstm   = (const float*)d_in[1];
    const float* z        = (const float*)d_in[2];
    const int*   edge_idx = (const int*)d_in[3];   // [2][N_EDGES]; row = first half
    const float* edge_attr= (const float*)d_in[4];
    const int*   node_idx = (const int*)d_in[5];
    const float* W1       = (const float*)d_in[6];
    const float* b1       = (const float*)d_in[7];
    const float* W2       = (const float*)d_in[8];
    const float* b2       = (const float*)d_in[9];
    float* out = (float*)d_out;

    // ws layout (256B-aligned slots)
    char* wsp = (char*)d_ws;
    size_t o = 0;
    auto alloc = [&](size_t bytes) { char* p = wsp + o; o = (o + bytes + 255) & ~(size_t)255; return p; };
    float* agg  = (float*)alloc((size_t)N_NODES * D_EDGE * 4);     // 19.2 MB
    int* cnt    = (int*)alloc((size_t)N_NODES * 4);
    int* cur    = (int*)alloc((size_t)N_NODES * 4);
    int* off    = (int*)alloc((size_t)N_NODES * 4);
    int* bsum   = (int*)alloc(512);
    int* bucket = (int*)alloc((size_t)BUCKET_CAP * 4);
    unsigned char* mask = (unsigned char*)alloc(N_NODES);
    unsigned short* W1t = (unsigned short*)alloc((size_t)D_HID * W1T_STRIDE * 2);
    unsigned short* W2t = (unsigned short*)alloc((size_t)D_OUT * D_HID * 2);

    hipMemsetAsync(mask, 0, N_NODES, stream);
    hipMemsetAsync(cnt, 0, (size_t)N_NODES * 4, stream);
    hipMemsetAsync(cur, 0, (size_t)N_NODES * 4, stream);

    prep_w1<<<(D_HID * W1T_STRIDE + 255) / 256, 256, 0, stream>>>(W1, W1t);
    prep_w2<<<(D_OUT * D_HID + 255) / 256, 256, 0, stream>>>(W2, W2t);

    mask_kernel<<<(N_AGENTS + 255) / 256, 256, 0, stream>>>(node_idx, mask);
    hist_kernel<<<(N_EDGES + 255) / 256, 256, 0, stream>>>(edge_idx, mask, cnt);
    scan_a<<<SCAN_BLOCKS, 256, 0, stream>>>(cnt, off, bsum);
    scan_b<<<1, 128, 0, stream>>>(bsum);
    scan_c<<<(N_NODES + 255) / 256, 256, 0, stream>>>(off, bsum);
    place_kernel<<<(N_EDGES + 255) / 256, 256, 0, stream>>>(edge_idx, mask, off, cur, bucket);
    gather_kernel<<<(N_NODES * D_EDGE + 255) / 256, 256, 0, stream>>>(
        edge_attr, mask, off, cnt, bucket, agg);

    mlp_mfma<<<N_AGENTS / 16, 256, 0, stream>>>(x, x_lstm, z, agg, node_idx,
                                                W1t, b1, W2t, b2, out);
}